// Round 1
// baseline (717.672 us; speedup 1.0000x reference)
//
#include <hip/hip_runtime.h>
#include <stdint.h>

#define B_ 8
#define N_ 4096
#define C_ 1024
#define H_ 16
#define M_ (B_*N_)          // 32768 rows
#define BH_ (B_*H_)         // 128

typedef unsigned short u16;
typedef unsigned int   u32;
typedef __bf16 bf16x8 __attribute__((ext_vector_type(8)));
typedef float  f32x4  __attribute__((ext_vector_type(4)));

// ---------- helpers ----------
__device__ __forceinline__ u16 f2bf(float f) {
  union { float f; u32 u; } x; x.f = f;
  u32 r = x.u + 0x7fffu + ((x.u >> 16) & 1u);   // RNE
  return (u16)(r >> 16);
}
__device__ __forceinline__ float bf2f(u16 b) {
  union { u32 u; float f; } x; x.u = ((u32)b) << 16;
  return x.f;
}
__device__ __forceinline__ void gload16(const void* g, void* l) {
  __builtin_amdgcn_global_load_lds(
      (const __attribute__((address_space(1))) void*)g,
      (__attribute__((address_space(3))) void*)l,
      16, 0, 0);
}

// ---------- 1) cast x fp32 -> bf16 ----------
__global__ void cast_f32_bf16(const float* __restrict__ in, u16* __restrict__ out, int n4) {
  int i = blockIdx.x * blockDim.x + threadIdx.x;
  const int stride = gridDim.x * blockDim.x;
  for (; i < n4; i += stride) {
    float4 v = reinterpret_cast<const float4*>(in)[i];
    u32 lo = (u32)f2bf(v.x) | ((u32)f2bf(v.y) << 16);
    u32 hi = (u32)f2bf(v.z) | ((u32)f2bf(v.w) << 16);
    uint2 o; o.x = lo; o.y = hi;
    reinterpret_cast<uint2*>(out)[i] = o;
  }
}

// ---------- 2) transpose + cast weights: [R][Cc] fp32 -> [Cc][R] bf16 ----------
__global__ void transpose_cast(const float* __restrict__ in, u16* __restrict__ out,
                               int R, int Cc) {
  __shared__ float t[32][33];
  const int bx = blockIdx.x * 32;   // col base (input)
  const int by = blockIdx.y * 32;   // row base (input)
  const int tx = threadIdx.x & 31;
  const int ty = threadIdx.x >> 5;  // 0..7
#pragma unroll
  for (int j = 0; j < 4; ++j) {
    const int r = by + ty + j * 8;
    t[ty + j * 8][tx] = in[(size_t)r * Cc + bx + tx];
  }
  __syncthreads();
#pragma unroll
  for (int j = 0; j < 4; ++j) {
    const int c = bx + ty + j * 8;                 // output row = input col
    out[(size_t)c * R + by + tx] = f2bf(t[tx][ty + j * 8]);
  }
}

// ---------- 3) GEMM: A[M][K] bf16 row-major, Bt[NC][K] bf16 (=B^T), + bias ----------
// m97 structure: 128x128 tile, BK=32, 4 waves (2x2), 16x16x32 bf16 MFMA,
// global_load_lds width 16, 2 barriers per K-step.
template <int NC, bool OUT_BF16>
__global__ void gemm_bt(const u16* __restrict__ A, const u16* __restrict__ Bt,
                        const float* __restrict__ bias, void* __restrict__ outp,
                        int K) {
  __shared__ __align__(16) u16 As[128 * 32];
  __shared__ __align__(16) u16 Bs[128 * 32];
  const int tid  = threadIdx.x;
  const int lane = tid & 63;
  const int w    = tid >> 6;
  const int wr   = (w >> 1) * 64;
  const int wc   = (w & 1) * 64;
  const int l15  = lane & 15;
  const int lk   = lane >> 4;          // 0..3
  const size_t brow = (size_t)blockIdx.y * 128;
  const size_t bcol = (size_t)blockIdx.x * 128;

  f32x4 acc[4][4] = {};

  const int r2  = tid >> 2;            // 0..63
  const int kof = (tid & 3) * 8;       // element offset within 32-wide K tile

  const int nK = K >> 5;
  for (int kt = 0; kt < nK; ++kt) {
    const size_t k0 = (size_t)kt * 32 + kof;
    gload16(A  + (brow + r2)      * K + k0, (char*)As + tid * 16);
    gload16(A  + (brow + 64 + r2) * K + k0, (char*)As + 4096 + tid * 16);
    gload16(Bt + (bcol + r2)      * K + k0, (char*)Bs + tid * 16);
    gload16(Bt + (bcol + 64 + r2) * K + k0, (char*)Bs + 4096 + tid * 16);
    __syncthreads();   // drains vmcnt -> staged tile visible

    bf16x8 a[4], b[4];
#pragma unroll
    for (int m = 0; m < 4; ++m)
      a[m] = *reinterpret_cast<const bf16x8*>(As + (wr + m * 16 + l15) * 32 + lk * 8);
#pragma unroll
    for (int n = 0; n < 4; ++n)
      b[n] = *reinterpret_cast<const bf16x8*>(Bs + (wc + n * 16 + l15) * 32 + lk * 8);
#pragma unroll
    for (int m = 0; m < 4; ++m)
#pragma unroll
      for (int n = 0; n < 4; ++n)
        acc[m][n] = __builtin_amdgcn_mfma_f32_16x16x32_bf16(a[m], b[n], acc[m][n], 0, 0, 0);
    __syncthreads();   // protect LDS before next stage
  }

  // epilogue: C/D frag layout col=lane&15, row=(lane>>4)*4+reg  [m89-verified]
#pragma unroll
  for (int n = 0; n < 4; ++n) {
    const size_t col = bcol + wc + n * 16 + l15;
    const float bv = bias[col];
#pragma unroll
    for (int m = 0; m < 4; ++m) {
      const size_t row0 = brow + wr + m * 16 + lk * 4;
#pragma unroll
      for (int r = 0; r < 4; ++r) {
        const float v = acc[m][n][r] + bv;
        if constexpr (OUT_BF16)
          ((u16*)outp)[(row0 + r) * NC + col] = f2bf(v);
        else
          ((float*)outp)[(row0 + r) * NC + col] = v;
      }
    }
  }
}

// ---------- 4) kv partial: per (b,h) and n-split, sum_n k_norm[n,d]*v[n,e] ----------
__global__ void kv_partial(const u16* __restrict__ qkv, float* __restrict__ part) {
  const int bh = blockIdx.x;           // 0..127
  const int sp = blockIdx.y;           // 0..7
  const int b  = bh >> 4, h = bh & 15;
  const int tid  = threadIdx.x;
  const int lane = tid & 63;
  const int g    = tid >> 6;           // stage group 0..3
  const int d    = tid & 63;           // owned d
  const int eb   = (tid >> 6) * 16;    // owned e block

  __shared__ __align__(16) float ks[4][64];
  __shared__ __align__(16) float vs[4][64];

  float acc[16];
#pragma unroll
  for (int j = 0; j < 16; ++j) acc[j] = 0.f;

  const size_t rowbase = ((size_t)b * N_ + (size_t)sp * 512) * 3072;
  const int kcol = 1024 + h * 64 + lane;
  const int vcol = 2048 + h * 64 + lane;

  for (int it = 0; it < 128; ++it) {
    const size_t roff = rowbase + (size_t)(it * 4 + g) * 3072;
    const float kraw = bf2f(qkv[roff + kcol]);
    const float vv   = bf2f(qkv[roff + vcol]);
    float s = kraw * kraw;
#pragma unroll
    for (int o = 32; o; o >>= 1) s += __shfl_xor(s, o);
    const float kn = kraw / fmaxf(sqrtf(s), 1e-12f);
    __syncthreads();                   // prior reads done before overwrite
    ks[g][lane] = kn;
    vs[g][lane] = vv;
    __syncthreads();
#pragma unroll
    for (int gg = 0; gg < 4; ++gg) {
      const float kd = ks[gg][d];
#pragma unroll
      for (int j = 0; j < 16; ++j) acc[j] += kd * vs[gg][eb + j];
    }
  }
  float* dst = part + ((size_t)sp * BH_ + bh) * 4096 + d * 64 + eb;
#pragma unroll
  for (int j = 0; j < 16; ++j) dst[j] = acc[j];
}

// ---------- 5) reduce 8 kv partials ----------
__global__ void kv_reduce(const float* __restrict__ part, float* __restrict__ kvf) {
  const int i = blockIdx.x * blockDim.x + threadIdx.x;  // 0..524287
  float s = 0.f;
#pragma unroll
  for (int sp = 0; sp < 8; ++sp) s += part[(size_t)sp * 524288 + i];
  kvf[i] = s;
}

// ---------- 6) attn = q_norm @ kv, write [B*N][C] bf16 ----------
__global__ void qkv_attn(const u16* __restrict__ qkv, const float* __restrict__ kvf,
                         u16* __restrict__ attn) {
  const int bh = blockIdx.x;           // 0..127
  const int ch = blockIdx.y;           // 0..31 (128 rows per chunk)
  const int b  = bh >> 4, h = bh & 15;
  const int tid  = threadIdx.x;
  const int lane = tid & 63;
  const int g    = tid >> 6;

  __shared__ __align__(16) float kvs[4096];  // kv[d][e]
  __shared__ __align__(16) float qs[32 * 64];

  const float* kvsrc = kvf + (size_t)bh * 4096;
#pragma unroll
  for (int j = 0; j < 4; ++j)
    *reinterpret_cast<float4*>(&kvs[tid * 4 + j * 1024]) =
        *reinterpret_cast<const float4*>(&kvsrc[tid * 4 + j * 1024]);
  __syncthreads();

  const int qcol = h * 64 + lane;
  for (int ph = 0; ph < 4; ++ph) {
    const int nbase = ch * 128 + ph * 32 + g * 8;
    // stage 8 q rows (wave-private region of qs), fused l2norm
#pragma unroll
    for (int r = 0; r < 8; ++r) {
      const size_t row = (size_t)b * N_ + nbase + r;
      const float qv = bf2f(qkv[row * 3072 + qcol]);
      float s = qv * qv;
#pragma unroll
      for (int o = 32; o; o >>= 1) s += __shfl_xor(s, o);
      qs[(g * 8 + r) * 64 + lane] = qv / fmaxf(sqrtf(s), 1e-12f);
    }
    float acc[8];
#pragma unroll
    for (int r = 0; r < 8; ++r) acc[r] = 0.f;
    for (int d0 = 0; d0 < 64; d0 += 4) {
      const float k0 = kvs[(d0 + 0) * 64 + lane];
      const float k1 = kvs[(d0 + 1) * 64 + lane];
      const float k2 = kvs[(d0 + 2) * 64 + lane];
      const float k3 = kvs[(d0 + 3) * 64 + lane];
#pragma unroll
      for (int r = 0; r < 8; ++r) {
        const float4 q4 = *reinterpret_cast<const float4*>(&qs[(g * 8 + r) * 64 + d0]);
        acc[r] = fmaf(q4.w, k3, fmaf(q4.z, k2, fmaf(q4.y, k1, fmaf(q4.x, k0, acc[r]))));
      }
    }
#pragma unroll
    for (int r = 0; r < 8; ++r) {
      const size_t row = (size_t)b * N_ + nbase + r;
      attn[row * 1024 + h * 64 + lane] = f2bf(acc[r]);
    }
  }
}

// ---------- workspace layout (bytes) ----------
#define WS_XB     0ull            // bf16 [32768][1024]   = 67108864
#define WS_QKV    67108864ull     // bf16 [32768][3072]   = 201326592
#define WS_ATTN   268435456ull    // bf16 [32768][1024]   = 67108864
#define WS_WQKV   335544320ull    // bf16 [3072][1024]    = 6291456
#define WS_WPROJ  341835776ull    // bf16 [1024][1024]    = 2097152
#define WS_PART   343932928ull    // f32  [8][128][4096]  = 16777216
#define WS_KVF    360710144ull    // f32  [128][4096]     = 2097152
// total ~346 MB

extern "C" void kernel_launch(void* const* d_in, const int* in_sizes, int n_in,
                              void* d_out, int out_size, void* d_ws, size_t ws_size,
                              hipStream_t stream) {
  const float* x      = (const float*)d_in[0];
  const float* qkv_w  = (const float*)d_in[1];
  const float* qkv_b  = (const float*)d_in[2];
  const float* proj_w = (const float*)d_in[3];
  const float* proj_b = (const float*)d_in[4];

  char* ws = (char*)d_ws;
  u16*   xb      = (u16*)(ws + WS_XB);
  u16*   qkv     = (u16*)(ws + WS_QKV);
  u16*   attn    = (u16*)(ws + WS_ATTN);
  u16*   wqkv_t  = (u16*)(ws + WS_WQKV);
  u16*   wproj_t = (u16*)(ws + WS_WPROJ);
  float* part    = (float*)(ws + WS_PART);
  float* kvf     = (float*)(ws + WS_KVF);

  // 1) x -> bf16
  cast_f32_bf16<<<2048, 256, 0, stream>>>(x, xb, (M_ * C_) / 4);
  // 2) weights -> bf16 transposed (B^T layout for GEMM)
  transpose_cast<<<dim3(96, 32), 256, 0, stream>>>(qkv_w, wqkv_t, 1024, 3072);
  transpose_cast<<<dim3(32, 32), 256, 0, stream>>>(proj_w, wproj_t, 1024, 1024);
  // 3) qkv = x @ qkv_w + b   (bf16 out)
  gemm_bt<3072, true><<<dim3(24, 256), 256, 0, stream>>>(xb, wqkv_t, qkv_b, qkv, 1024);
  // 4) kv state (k l2norm fused), split-K partials then reduce
  kv_partial<<<dim3(128, 8), 256, 0, stream>>>(qkv, part);
  kv_reduce<<<2048, 256, 0, stream>>>(part, kvf);
  // 5) attn = q_norm @ kv
  qkv_attn<<<dim3(128, 32), 256, 0, stream>>>(qkv, kvf, attn);
  // 6) out = attn @ proj_w + b  (fp32 out)
  gemm_bt<1024, false><<<dim3(8, 256), 256, 0, stream>>>(attn, wproj_t, proj_b, d_out, 1024);
}

// Round 2
// 669.976 us; speedup vs baseline: 1.0712x; 1.0712x over previous
//
#include <hip/hip_runtime.h>
#include <stdint.h>

#define B_ 8
#define N_ 4096
#define C_ 1024
#define H_ 16
#define M_ (B_*N_)          // 32768 rows
#define BH_ (B_*H_)         // 128

typedef unsigned short u16;
typedef unsigned int   u32;
typedef __bf16 bf16x8 __attribute__((ext_vector_type(8)));
typedef float  f32x4  __attribute__((ext_vector_type(4)));

// ---------- helpers ----------
__device__ __forceinline__ u16 f2bf(float f) {
  union { float f; u32 u; } x; x.f = f;
  u32 r = x.u + 0x7fffu + ((x.u >> 16) & 1u);   // RNE
  return (u16)(r >> 16);
}
__device__ __forceinline__ float bf2f(u16 b) {
  union { u32 u; float f; } x; x.u = ((u32)b) << 16;
  return x.f;
}
__device__ __forceinline__ void gload16(const void* g, void* l) {
  __builtin_amdgcn_global_load_lds(
      (const __attribute__((address_space(1))) void*)g,
      (__attribute__((address_space(3))) void*)l,
      16, 0, 0);
}

// ---------- 1) cast x fp32 -> bf16 ----------
__global__ void cast_f32_bf16(const float* __restrict__ in, u16* __restrict__ out, int n4) {
  int i = blockIdx.x * blockDim.x + threadIdx.x;
  const int stride = gridDim.x * blockDim.x;
  for (; i < n4; i += stride) {
    float4 v = reinterpret_cast<const float4*>(in)[i];
    u32 lo = (u32)f2bf(v.x) | ((u32)f2bf(v.y) << 16);
    u32 hi = (u32)f2bf(v.z) | ((u32)f2bf(v.w) << 16);
    uint2 o; o.x = lo; o.y = hi;
    reinterpret_cast<uint2*>(out)[i] = o;
  }
}

// ---------- 2) transpose + cast weights: [R][Cc] fp32 -> [Cc][R] bf16 ----------
__global__ void transpose_cast(const float* __restrict__ in, u16* __restrict__ out,
                               int R, int Cc) {
  __shared__ float t[32][33];
  const int bx = blockIdx.x * 32;
  const int by = blockIdx.y * 32;
  const int tx = threadIdx.x & 31;
  const int ty = threadIdx.x >> 5;
#pragma unroll
  for (int j = 0; j < 4; ++j) {
    const int r = by + ty + j * 8;
    t[ty + j * 8][tx] = in[(size_t)r * Cc + bx + tx];
  }
  __syncthreads();
#pragma unroll
  for (int j = 0; j < 4; ++j) {
    const int c = bx + ty + j * 8;
    out[(size_t)c * R + by + tx] = f2bf(t[tx][ty + j * 8]);
  }
}

// ---------- 3) 256x256 8-phase GEMM (T1+T2+T3+T4+T5) ----------
// A[M][K] bf16 row-major, Bt[NC][K] bf16 (=B^T), + bias.
// 8 waves = 2(M)x4(N); per-wave 128x64 output INTERLEAVED across tile halves:
//   rows = mh*128 + wm*64 + mf*16, cols = nh*128 + wn*32 + nf*16.
// Quadrant phases (mh,nh): (0,0),(0,1),(1,0),(1,1) -> half needs/frees staggered.
// Stage slots per group t: ph1:(t+1).Ah1  ph2:(t+1).Bh1  ph3:(t+2).Ah0  ph4:(t+2).Bh0
// Gate: vmcnt(4) at ph4 (leaves exactly the two ph3/ph4 halves in flight).
// LDS st_16x32-style swizzle: linear dest (global_load_lds) + inverse-swizzled
// global SOURCE + swizzled ds_read (chunk ^= row&7 on 16B chunks).
template <int NC, bool OUT_BF16>
__global__ __launch_bounds__(512) void gemm256(const u16* __restrict__ A,
                                               const u16* __restrict__ Bt,
                                               const float* __restrict__ bias,
                                               void* __restrict__ outp,
                                               int K, int cpx) {
  __shared__ __align__(16) u16 As[2][256][64];   // 64 KB
  __shared__ __align__(16) u16 Bs[2][256][64];   // 64 KB
  const int tid  = threadIdx.x;
  const int lane = tid & 63;
  const int w    = tid >> 6;
  const int wm   = (w >> 2) & 1;
  const int wn   = w & 3;
  const int l15  = lane & 15;
  const int lk   = lane >> 4;

  // T1: bijective XCD swizzle (nwg % 8 == 0 for both uses)
  const int bid = blockIdx.x;
  const int wg  = (bid & 7) * cpx + (bid >> 3);
  const size_t brow = (size_t)(wg & 127) * 256;   // M/256 = 128 row tiles
  const size_t bcol = (size_t)(wg >> 7) * 256;

  const int KT = K >> 6;
  f32x4 acc[2][2][4][2] = {};   // [mh][nh][mf][nf]

  // stage one 128-row half-tile (16 KB) = 2 x global_load_lds per thread
  auto stage = [&](const u16* __restrict__ src, size_t rowbase, int kt,
                   u16* lds_tile, int h) {
#pragma unroll
    for (int is = 0; is < 2; ++is) {
      const int lin   = is * 8192 + tid * 16;       // byte within 16KB half
      const int row   = lin >> 7;                   // 0..127
      const int chunk = ((lin >> 4) & 7) ^ (row & 7);  // inverse swizzle on SOURCE
      gload16(src + (rowbase + (size_t)(h * 128 + row)) * K + kt * 64 + chunk * 8,
              (char*)lds_tile + h * 16384 + lin);
    }
  };
  auto fragA = [&](const u16* tb, int mh, int mf, int kc) -> bf16x8 {
    const int row   = mh * 128 + wm * 64 + mf * 16 + l15;
    const int chunk = ((kc << 2) | lk) ^ (row & 7);
    return *reinterpret_cast<const bf16x8*>((const char*)tb + row * 128 + chunk * 16);
  };
  auto fragB = [&](const u16* tb, int nh, int nf, int kc) -> bf16x8 {
    const int row   = nh * 128 + wn * 32 + nf * 16 + l15;
    const int chunk = ((kc << 2) | lk) ^ (row & 7);
    return *reinterpret_cast<const bf16x8*>((const char*)tb + row * 128 + chunk * 16);
  };

#define PHASE(MH, NH, STAGE_STMT, GATE_STMT) do {                              \
    bf16x8 af[4][2], bfm[2][2];                                                \
    _Pragma("unroll") for (int mf = 0; mf < 4; ++mf)                           \
      _Pragma("unroll") for (int kc = 0; kc < 2; ++kc)                         \
        af[mf][kc] = fragA(curA, MH, mf, kc);                                  \
    _Pragma("unroll") for (int nf = 0; nf < 2; ++nf)                           \
      _Pragma("unroll") for (int kc = 0; kc < 2; ++kc)                         \
        bfm[nf][kc] = fragB(curB, NH, nf, kc);                                 \
    STAGE_STMT;                                                                \
    GATE_STMT;                                                                 \
    __builtin_amdgcn_s_barrier();                                              \
    __builtin_amdgcn_s_setprio(1);                                             \
    _Pragma("unroll") for (int mf = 0; mf < 4; ++mf)                           \
      _Pragma("unroll") for (int nf = 0; nf < 2; ++nf)                         \
        _Pragma("unroll") for (int kc = 0; kc < 2; ++kc)                       \
          acc[MH][NH][mf][nf] = __builtin_amdgcn_mfma_f32_16x16x32_bf16(       \
              af[mf][kc], bfm[nf][kc], acc[MH][NH][mf][nf], 0, 0, 0);          \
    __builtin_amdgcn_s_setprio(0);                                             \
    __builtin_amdgcn_s_barrier();                                              \
  } while (0)

  // prologue: tile0 fully + tile1 Ah0/Bh0
  stage(A,  brow, 0, &As[0][0][0], 0);
  stage(Bt, bcol, 0, &Bs[0][0][0], 0);
  stage(A,  brow, 0, &As[0][0][0], 1);
  stage(Bt, bcol, 0, &Bs[0][0][0], 1);
  stage(A,  brow, 1, &As[1][0][0], 0);
  stage(Bt, bcol, 1, &Bs[1][0][0], 0);
  asm volatile("s_waitcnt vmcnt(4)" ::: "memory");
  __builtin_amdgcn_s_barrier();

  for (int t = 0; t < KT; ++t) {
    const u16* curA = &As[t & 1][0][0];
    const u16* curB = &Bs[t & 1][0][0];
    u16* nA  = &As[(t + 1) & 1][0][0];
    u16* nB  = &Bs[(t + 1) & 1][0][0];
    u16* n2A = &As[t & 1][0][0];
    u16* n2B = &Bs[t & 1][0][0];
    const bool s1 = (t + 1) < KT;
    const bool s2 = (t + 2) < KT;
    PHASE(0, 0, { if (s1) stage(A,  brow, t + 1, nA, 1); }, {});
    PHASE(0, 1, { if (s1) stage(Bt, bcol, t + 1, nB, 1); }, {});
    PHASE(1, 0, { if (s2) stage(A,  brow, t + 2, n2A, 0); }, {});
    PHASE(1, 1, { if (s2) stage(Bt, bcol, t + 2, n2B, 0); },
          { if (s2) { asm volatile("s_waitcnt vmcnt(4)" ::: "memory"); }
            else    { asm volatile("s_waitcnt vmcnt(0)" ::: "memory"); } });
  }
#undef PHASE

  // epilogue: C/D layout col=lane&15, row=(lane>>4)*4+reg  [m89-verified]
#pragma unroll
  for (int mh = 0; mh < 2; ++mh)
#pragma unroll
  for (int nh = 0; nh < 2; ++nh)
#pragma unroll
  for (int mf = 0; mf < 4; ++mf)
#pragma unroll
  for (int nf = 0; nf < 2; ++nf) {
    const size_t col = bcol + nh * 128 + wn * 32 + nf * 16 + l15;
    const float bv = bias[col];
    const size_t row0 = brow + mh * 128 + wm * 64 + mf * 16 + lk * 4;
#pragma unroll
    for (int r = 0; r < 4; ++r) {
      const float v = acc[mh][nh][mf][nf][r] + bv;
      if constexpr (OUT_BF16)
        ((u16*)outp)[(row0 + r) * NC + col] = f2bf(v);
      else
        ((float*)outp)[(row0 + r) * NC + col] = v;
    }
  }
}

// ---------- 4) kv partial: per (b,h) and n-split, sum_n k_norm[n,d]*v[n,e] ----------
// 16 rows per barrier pair (4x fewer barriers than before)
__global__ void kv_partial(const u16* __restrict__ qkv, float* __restrict__ part) {
  const int bh = blockIdx.x;           // 0..127
  const int sp = blockIdx.y;           // 0..7
  const int b  = bh >> 4, h = bh & 15;
  const int tid  = threadIdx.x;
  const int lane = tid & 63;
  const int g    = tid >> 6;
  const int d    = tid & 63;
  const int eb   = (tid >> 6) * 16;

  __shared__ __align__(16) float ks[16][64];
  __shared__ __align__(16) float vs[16][64];

  float acc[16];
#pragma unroll
  for (int j = 0; j < 16; ++j) acc[j] = 0.f;

  const size_t rowbase = ((size_t)b * N_ + (size_t)sp * 512) * 3072;
  const int kcol = 1024 + h * 64 + lane;
  const int vcol = 2048 + h * 64 + lane;

  for (int it = 0; it < 32; ++it) {
    float kn[4], vv[4];
#pragma unroll
    for (int j = 0; j < 4; ++j) {
      const size_t roff = rowbase + (size_t)(it * 16 + g * 4 + j) * 3072;
      const float kraw = bf2f(qkv[roff + kcol]);
      vv[j] = bf2f(qkv[roff + vcol]);
      float s = kraw * kraw;
#pragma unroll
      for (int o = 32; o; o >>= 1) s += __shfl_xor(s, o);
      kn[j] = kraw / fmaxf(sqrtf(s), 1e-12f);
    }
    __syncthreads();                   // prior reads done before overwrite
#pragma unroll
    for (int j = 0; j < 4; ++j) {
      ks[g * 4 + j][lane] = kn[j];
      vs[g * 4 + j][lane] = vv[j];
    }
    __syncthreads();
#pragma unroll
    for (int gg = 0; gg < 16; ++gg) {
      const float kd = ks[gg][d];
#pragma unroll
      for (int j2 = 0; j2 < 16; ++j2) acc[j2] += kd * vs[gg][eb + j2];
    }
  }
  float* dst = part + ((size_t)sp * BH_ + bh) * 4096 + d * 64 + eb;
#pragma unroll
  for (int j = 0; j < 16; ++j) dst[j] = acc[j];
}

// ---------- 5) reduce 8 kv partials ----------
__global__ void kv_reduce(const float* __restrict__ part, float* __restrict__ kvf) {
  const int i = blockIdx.x * blockDim.x + threadIdx.x;
  float s = 0.f;
#pragma unroll
  for (int sp = 0; sp < 8; ++sp) s += part[(size_t)sp * 524288 + i];
  kvf[i] = s;
}

// ---------- 6) attn = q_norm @ kv, write [B*N][C] bf16 ----------
__global__ void qkv_attn(const u16* __restrict__ qkv, const float* __restrict__ kvf,
                         u16* __restrict__ attn) {
  const int bh = blockIdx.x;
  const int ch = blockIdx.y;
  const int b  = bh >> 4, h = bh & 15;
  const int tid  = threadIdx.x;
  const int lane = tid & 63;
  const int g    = tid >> 6;

  __shared__ __align__(16) float kvs[4096];
  __shared__ __align__(16) float qs[32 * 64];

  const float* kvsrc = kvf + (size_t)bh * 4096;
#pragma unroll
  for (int j = 0; j < 4; ++j)
    *reinterpret_cast<float4*>(&kvs[tid * 4 + j * 1024]) =
        *reinterpret_cast<const float4*>(&kvsrc[tid * 4 + j * 1024]);
  __syncthreads();

  const int qcol = h * 64 + lane;
  for (int ph = 0; ph < 4; ++ph) {
    const int nbase = ch * 128 + ph * 32 + g * 8;
#pragma unroll
    for (int r = 0; r < 8; ++r) {
      const size_t row = (size_t)b * N_ + nbase + r;
      const float qv = bf2f(qkv[row * 3072 + qcol]);
      float s = qv * qv;
#pragma unroll
      for (int o = 32; o; o >>= 1) s += __shfl_xor(s, o);
      qs[(g * 8 + r) * 64 + lane] = qv / fmaxf(sqrtf(s), 1e-12f);
    }
    float acc[8];
#pragma unroll
    for (int r = 0; r < 8; ++r) acc[r] = 0.f;
    for (int d0 = 0; d0 < 64; d0 += 4) {
      const float k0 = kvs[(d0 + 0) * 64 + lane];
      const float k1 = kvs[(d0 + 1) * 64 + lane];
      const float k2 = kvs[(d0 + 2) * 64 + lane];
      const float k3 = kvs[(d0 + 3) * 64 + lane];
#pragma unroll
      for (int r = 0; r < 8; ++r) {
        const float4 q4 = *reinterpret_cast<const float4*>(&qs[(g * 8 + r) * 64 + d0]);
        acc[r] = fmaf(q4.w, k3, fmaf(q4.z, k2, fmaf(q4.y, k1, fmaf(q4.x, k0, acc[r]))));
      }
    }
#pragma unroll
    for (int r = 0; r < 8; ++r) {
      const size_t row = (size_t)b * N_ + nbase + r;
      attn[row * 1024 + h * 64 + lane] = f2bf(acc[r]);
    }
  }
}

// ---------- workspace layout (bytes) ----------
#define WS_XB     0ull            // bf16 [32768][1024]
#define WS_QKV    67108864ull     // bf16 [32768][3072]
#define WS_ATTN   268435456ull    // bf16 [32768][1024]
#define WS_WQKV   335544320ull    // bf16 [3072][1024]
#define WS_WPROJ  341835776ull    // bf16 [1024][1024]
#define WS_PART   343932928ull    // f32  [8][128][4096]
#define WS_KVF    360710144ull    // f32  [128][4096]

extern "C" void kernel_launch(void* const* d_in, const int* in_sizes, int n_in,
                              void* d_out, int out_size, void* d_ws, size_t ws_size,
                              hipStream_t stream) {
  const float* x      = (const float*)d_in[0];
  const float* qkv_w  = (const float*)d_in[1];
  const float* qkv_b  = (const float*)d_in[2];
  const float* proj_w = (const float*)d_in[3];
  const float* proj_b = (const float*)d_in[4];

  char* ws = (char*)d_ws;
  u16*   xb      = (u16*)(ws + WS_XB);
  u16*   qkv     = (u16*)(ws + WS_QKV);
  u16*   attn    = (u16*)(ws + WS_ATTN);
  u16*   wqkv_t  = (u16*)(ws + WS_WQKV);
  u16*   wproj_t = (u16*)(ws + WS_WPROJ);
  float* part    = (float*)(ws + WS_PART);
  float* kvf     = (float*)(ws + WS_KVF);

  cast_f32_bf16<<<2048, 256, 0, stream>>>(x, xb, (M_ * C_) / 4);
  transpose_cast<<<dim3(96, 32), 256, 0, stream>>>(qkv_w, wqkv_t, 1024, 3072);
  transpose_cast<<<dim3(32, 32), 256, 0, stream>>>(proj_w, wproj_t, 1024, 1024);
  // qkv = x @ qkv_w + b : 1536 wgs (128 row-tiles x 12 col-tiles), cpx = 1536/8
  gemm256<3072, true><<<1536, 512, 0, stream>>>(xb, wqkv_t, qkv_b, qkv, 1024, 192);
  kv_partial<<<dim3(128, 8), 256, 0, stream>>>(qkv, part);
  kv_reduce<<<2048, 256, 0, stream>>>(part, kvf);
  qkv_attn<<<dim3(128, 32), 256, 0, stream>>>(qkv, kvf, attn);
  // out = attn @ proj_w + b : 512 wgs (128 x 4), cpx = 512/8
  gemm256<1024, false><<<512, 512, 0, stream>>>(attn, wproj_t, proj_b, d_out, 1024, 64);
}

// Round 3
// 505.175 us; speedup vs baseline: 1.4206x; 1.3262x over previous
//
#include <hip/hip_runtime.h>
#include <stdint.h>

#define B_ 8
#define N_ 4096
#define C_ 1024
#define H_ 16
#define M_ (B_*N_)          // 32768 rows
#define BH_ (B_*H_)         // 128

typedef unsigned short u16;
typedef unsigned int   u32;
typedef __bf16 bf16x8 __attribute__((ext_vector_type(8)));
typedef float  f32x4  __attribute__((ext_vector_type(4)));

// ---------- helpers ----------
__device__ __forceinline__ u16 f2bf(float f) {
  union { float f; u32 u; } x; x.f = f;
  u32 r = x.u + 0x7fffu + ((x.u >> 16) & 1u);   // RNE
  return (u16)(r >> 16);
}
__device__ __forceinline__ float bf2f(u16 b) {
  union { u32 u; float f; } x; x.u = ((u32)b) << 16;
  return x.f;
}
__device__ __forceinline__ void gload16(const void* g, void* l) {
  __builtin_amdgcn_global_load_lds(
      (const __attribute__((address_space(1))) void*)g,
      (__attribute__((address_space(3))) void*)l,
      16, 0, 0);
}
__device__ __forceinline__ void unpack8(uint4 r, float* f) {
  const u32 w[4] = {r.x, r.y, r.z, r.w};
#pragma unroll
  for (int i = 0; i < 4; ++i) {
    f[2*i]   = bf2f((u16)(w[i] & 0xffffu));
    f[2*i+1] = bf2f((u16)(w[i] >> 16));
  }
}
__device__ __forceinline__ uint4 pack8(const float* f) {
  uint4 r; u32* w = (u32*)&r;
#pragma unroll
  for (int i = 0; i < 4; ++i)
    w[i] = (u32)f2bf(f[2*i]) | ((u32)f2bf(f[2*i+1]) << 16);
  return r;
}

// ---------- 1) cast x fp32 -> bf16 ----------
__global__ void cast_f32_bf16(const float* __restrict__ in, u16* __restrict__ out, int n4) {
  int i = blockIdx.x * blockDim.x + threadIdx.x;
  const int stride = gridDim.x * blockDim.x;
  for (; i < n4; i += stride) {
    float4 v = reinterpret_cast<const float4*>(in)[i];
    u32 lo = (u32)f2bf(v.x) | ((u32)f2bf(v.y) << 16);
    u32 hi = (u32)f2bf(v.z) | ((u32)f2bf(v.w) << 16);
    uint2 o; o.x = lo; o.y = hi;
    reinterpret_cast<uint2*>(out)[i] = o;
  }
}

// ---------- 2) transpose + cast weights: [R][Cc] fp32 -> [Cc][R] bf16 ----------
__global__ void transpose_cast(const float* __restrict__ in, u16* __restrict__ out,
                               int R, int Cc) {
  __shared__ float t[32][33];
  const int bx = blockIdx.x * 32;
  const int by = blockIdx.y * 32;
  const int tx = threadIdx.x & 31;
  const int ty = threadIdx.x >> 5;
#pragma unroll
  for (int j = 0; j < 4; ++j) {
    const int r = by + ty + j * 8;
    t[ty + j * 8][tx] = in[(size_t)r * Cc + bx + tx];
  }
  __syncthreads();
#pragma unroll
  for (int j = 0; j < 4; ++j) {
    const int c = bx + ty + j * 8;
    out[(size_t)c * R + by + tx] = f2bf(t[tx][ty + j * 8]);
  }
}

// ---------- 3) 256x256 8-phase GEMM, frag-reuse schedule ----------
// Phases per K-tile: (0,0) (0,1) (1,1) (1,0); afA reused ph0/ph1, bf1 ph1/ph2,
// afB ph2/ph3, bf0 ph0/ph3 -> 24 ds_read_b128 per K-tile per wave.
// Stage slots: ph0:(t+1)Ah1  ph1:(t+1)Bh1  ph2:(t+2)Ah0  ph3:(t+2)Bh0 + vmcnt(4).
template <int NC, bool OUT_BF16>
__global__ __launch_bounds__(512) void gemm256(const u16* __restrict__ A,
                                               const u16* __restrict__ Bt,
                                               const float* __restrict__ bias,
                                               void* __restrict__ outp,
                                               int K, int cpx) {
  __shared__ __align__(16) u16 As[2][256][64];   // 64 KB
  __shared__ __align__(16) u16 Bs[2][256][64];   // 64 KB
  const int tid  = threadIdx.x;
  const int lane = tid & 63;
  const int w    = tid >> 6;
  const int wm   = (w >> 2) & 1;
  const int wn   = w & 3;
  const int l15  = lane & 15;
  const int lk   = lane >> 4;

  const int bid = blockIdx.x;
  const int wg  = (bid & 7) * cpx + (bid >> 3);
  const size_t brow = (size_t)(wg & 127) * 256;
  const size_t bcol = (size_t)(wg >> 7) * 256;

  const int KT = K >> 6;
  f32x4 acc[2][2][4][2] = {};   // [mh][nh][mf][nf]

  auto stage = [&](const u16* __restrict__ src, size_t rowbase, int kt,
                   u16* lds_tile, int h) {
#pragma unroll
    for (int is = 0; is < 2; ++is) {
      const int lin   = is * 8192 + tid * 16;
      const int row   = lin >> 7;
      const int chunk = ((lin >> 4) & 7) ^ (row & 7);
      gload16(src + (rowbase + (size_t)(h * 128 + row)) * K + kt * 64 + chunk * 8,
              (char*)lds_tile + h * 16384 + lin);
    }
  };
  auto fragA = [&](const u16* tb, int mh, int mf, int kc) -> bf16x8 {
    const int row   = mh * 128 + wm * 64 + mf * 16 + l15;
    const int chunk = ((kc << 2) | lk) ^ (row & 7);
    return *reinterpret_cast<const bf16x8*>((const char*)tb + row * 128 + chunk * 16);
  };
  auto fragB = [&](const u16* tb, int nh, int nf, int kc) -> bf16x8 {
    const int row   = nh * 128 + wn * 32 + nf * 16 + l15;
    const int chunk = ((kc << 2) | lk) ^ (row & 7);
    return *reinterpret_cast<const bf16x8*>((const char*)tb + row * 128 + chunk * 16);
  };

#define MFMA_Q(AF, BF, MH, NH) do {                                            \
    __builtin_amdgcn_s_barrier();                                              \
    __builtin_amdgcn_s_setprio(1);                                             \
    _Pragma("unroll") for (int mf = 0; mf < 4; ++mf)                           \
      _Pragma("unroll") for (int nf = 0; nf < 2; ++nf)                         \
        _Pragma("unroll") for (int kc = 0; kc < 2; ++kc)                       \
          acc[MH][NH][mf][nf] = __builtin_amdgcn_mfma_f32_16x16x32_bf16(       \
              AF[mf][kc], BF[nf][kc], acc[MH][NH][mf][nf], 0, 0, 0);           \
    __builtin_amdgcn_s_setprio(0);                                             \
    __builtin_amdgcn_s_barrier();                                              \
  } while (0)

  // prologue: tile0 fully + tile1 Ah0/Bh0 (12 loads); vmcnt(4) -> tile0 done
  stage(A,  brow, 0, &As[0][0][0], 0);
  stage(Bt, bcol, 0, &Bs[0][0][0], 0);
  stage(A,  brow, 0, &As[0][0][0], 1);
  stage(Bt, bcol, 0, &Bs[0][0][0], 1);
  stage(A,  brow, 1, &As[1][0][0], 0);
  stage(Bt, bcol, 1, &Bs[1][0][0], 0);
  asm volatile("s_waitcnt vmcnt(4)" ::: "memory");
  __builtin_amdgcn_s_barrier();

  for (int t = 0; t < KT; ++t) {
    const u16* curA = &As[t & 1][0][0];
    const u16* curB = &Bs[t & 1][0][0];
    u16* nA  = &As[(t + 1) & 1][0][0];
    u16* nB  = &Bs[(t + 1) & 1][0][0];
    u16* n2A = &As[t & 1][0][0];
    u16* n2B = &Bs[t & 1][0][0];
    const bool s1 = (t + 1) < KT;
    const bool s2 = (t + 2) < KT;

    bf16x8 afA[4][2], afB[4][2], bf0[2][2], bf1[2][2];

    // ph0: (0,0)
#pragma unroll
    for (int mf = 0; mf < 4; ++mf)
#pragma unroll
      for (int kc = 0; kc < 2; ++kc) afA[mf][kc] = fragA(curA, 0, mf, kc);
#pragma unroll
    for (int nf = 0; nf < 2; ++nf)
#pragma unroll
      for (int kc = 0; kc < 2; ++kc) bf0[nf][kc] = fragB(curB, 0, nf, kc);
    if (s1) stage(A, brow, t + 1, nA, 1);
    MFMA_Q(afA, bf0, 0, 0);

    // ph1: (0,1)
#pragma unroll
    for (int nf = 0; nf < 2; ++nf)
#pragma unroll
      for (int kc = 0; kc < 2; ++kc) bf1[nf][kc] = fragB(curB, 1, nf, kc);
    if (s1) stage(Bt, bcol, t + 1, nB, 1);
    MFMA_Q(afA, bf1, 0, 1);

    // ph2: (1,1)
#pragma unroll
    for (int mf = 0; mf < 4; ++mf)
#pragma unroll
      for (int kc = 0; kc < 2; ++kc) afB[mf][kc] = fragA(curA, 1, mf, kc);
    if (s2) stage(A, brow, t + 2, n2A, 0);
    MFMA_Q(afB, bf1, 1, 1);

    // ph3: (1,0)
    if (s2) {
      stage(Bt, bcol, t + 2, n2B, 0);
      asm volatile("s_waitcnt vmcnt(4)" ::: "memory");
    } else {
      asm volatile("s_waitcnt vmcnt(0)" ::: "memory");
    }
    MFMA_Q(afB, bf0, 1, 0);
  }
#undef MFMA_Q

  // epilogue: C/D layout col=lane&15, row=(lane>>4)*4+reg
#pragma unroll
  for (int mh = 0; mh < 2; ++mh)
#pragma unroll
  for (int nh = 0; nh < 2; ++nh)
#pragma unroll
  for (int mf = 0; mf < 4; ++mf)
#pragma unroll
  for (int nf = 0; nf < 2; ++nf) {
    const size_t col = bcol + nh * 128 + wn * 32 + nf * 16 + l15;
    const float bv = bias[col];
    const size_t row0 = brow + mh * 128 + wm * 64 + mf * 16 + lk * 4;
#pragma unroll
    for (int r = 0; r < 4; ++r) {
      const float v = acc[mh][nh][mf][nf][r] + bv;
      if constexpr (OUT_BF16)
        ((u16*)outp)[(row0 + r) * NC + col] = f2bf(v);
      else
        ((float*)outp)[(row0 + r) * NC + col] = v;
    }
  }
}

// ---------- 4) prep: q-norm in place; KT[bh][d][n] (k-norm); VT[bh][e][n] ----------
__global__ void prep(u16* __restrict__ qkv, u16* __restrict__ KT, u16* __restrict__ VT) {
  const int bh = blockIdx.x, nt = blockIdx.y;
  const int b = bh >> 4, h = bh & 15;
  const int n0 = nt * 64;
  const int tid = threadIdx.x;
  __shared__ float tk[64 * 65];

  // --- Q: normalize in place ---
#pragma unroll
  for (int it = 0; it < 2; ++it) {
    const int idx = it * 256 + tid;
    const int r = idx >> 3, c8 = idx & 7;
    const size_t addr = ((size_t)(b * N_ + n0 + r)) * 3072 + h * 64 + c8 * 8;
    uint4 raw = *reinterpret_cast<const uint4*>(qkv + addr);
    float f[8]; unpack8(raw, f);
    float ss = 0.f;
#pragma unroll
    for (int j = 0; j < 8; ++j) ss += f[j] * f[j];
    ss += __shfl_xor(ss, 1); ss += __shfl_xor(ss, 2); ss += __shfl_xor(ss, 4);
    const float sc = 1.f / fmaxf(sqrtf(ss), 1e-12f);
#pragma unroll
    for (int j = 0; j < 8; ++j) f[j] *= sc;
    *reinterpret_cast<uint4*>(qkv + addr) = pack8(f);
  }

  // --- K: normalize, transpose via LDS, write KT ---
#pragma unroll
  for (int it = 0; it < 2; ++it) {
    const int idx = it * 256 + tid;
    const int r = idx >> 3, c8 = idx & 7;
    const size_t addr = ((size_t)(b * N_ + n0 + r)) * 3072 + 1024 + h * 64 + c8 * 8;
    uint4 raw = *reinterpret_cast<const uint4*>(qkv + addr);
    float f[8]; unpack8(raw, f);
    float ss = 0.f;
#pragma unroll
    for (int j = 0; j < 8; ++j) ss += f[j] * f[j];
    ss += __shfl_xor(ss, 1); ss += __shfl_xor(ss, 2); ss += __shfl_xor(ss, 4);
    const float sc = 1.f / fmaxf(sqrtf(ss), 1e-12f);
#pragma unroll
    for (int j = 0; j < 8; ++j) tk[r * 65 + c8 * 8 + j] = f[j] * sc;
  }
  __syncthreads();
  {
    const int d = tid >> 2, nq = tid & 3;
    float v[16];
#pragma unroll
    for (int j = 0; j < 16; ++j) v[j] = tk[(nq * 16 + j) * 65 + d];
    u16* dst = KT + ((size_t)(bh * 64 + d)) * 4096 + n0 + nq * 16;
    *reinterpret_cast<uint4*>(dst)     = pack8(v);
    *reinterpret_cast<uint4*>(dst + 8) = pack8(v + 8);
  }
  __syncthreads();

  // --- V: transpose (no norm), write VT ---
#pragma unroll
  for (int it = 0; it < 2; ++it) {
    const int idx = it * 256 + tid;
    const int r = idx >> 3, c8 = idx & 7;
    const size_t addr = ((size_t)(b * N_ + n0 + r)) * 3072 + 2048 + h * 64 + c8 * 8;
    uint4 raw = *reinterpret_cast<const uint4*>(qkv + addr);
    float f[8]; unpack8(raw, f);
#pragma unroll
    for (int j = 0; j < 8; ++j) tk[r * 65 + c8 * 8 + j] = f[j];
  }
  __syncthreads();
  {
    const int e = tid >> 2, nq = tid & 3;
    float v[16];
#pragma unroll
    for (int j = 0; j < 16; ++j) v[j] = tk[(nq * 16 + j) * 65 + e];
    u16* dst = VT + ((size_t)(bh * 64 + e)) * 4096 + n0 + nq * 16;
    *reinterpret_cast<uint4*>(dst)     = pack8(v);
    *reinterpret_cast<uint4*>(dst + 8) = pack8(v + 8);
  }
}

// ---------- 5) kv_gemm: kvT[e][d] = sum_n VT[e][n]*KT[d][n], split-K=4 ----------
__global__ void kv_gemm(const u16* __restrict__ VT, const u16* __restrict__ KT,
                        float* __restrict__ part) {
  const int bh = blockIdx.x, sp = blockIdx.y;
  __shared__ __align__(16) u16 Vs[64 * 64];   // 8KB
  __shared__ __align__(16) u16 Ks[64 * 64];   // 8KB
  const int tid  = threadIdx.x;
  const int lane = tid & 63;
  const int w    = tid >> 6;         // 0..3
  const int wm   = w >> 1, wn = w & 1;
  const int l15  = lane & 15;
  const int lk   = lane >> 4;

  f32x4 acc[2][2] = {};

  for (int kt = 0; kt < 16; ++kt) {
    const size_t k0 = (size_t)sp * 1024 + kt * 64;
#pragma unroll
    for (int is = 0; is < 2; ++is) {
      const int lin   = is * 4096 + tid * 16;
      const int row   = lin >> 7;
      const int chunk = ((lin >> 4) & 7) ^ (row & 7);
      gload16(VT + ((size_t)(bh * 64 + row)) * 4096 + k0 + chunk * 8, (char*)Vs + lin);
      gload16(KT + ((size_t)(bh * 64 + row)) * 4096 + k0 + chunk * 8, (char*)Ks + lin);
    }
    __syncthreads();
    bf16x8 fa[2][2], fb[2][2];
#pragma unroll
    for (int mf = 0; mf < 2; ++mf)
#pragma unroll
      for (int kc = 0; kc < 2; ++kc) {
        const int row = wm * 32 + mf * 16 + l15;
        const int chunk = ((kc << 2) | lk) ^ (row & 7);
        fa[mf][kc] = *reinterpret_cast<const bf16x8*>((const char*)Vs + row * 128 + chunk * 16);
      }
#pragma unroll
    for (int nf = 0; nf < 2; ++nf)
#pragma unroll
      for (int kc = 0; kc < 2; ++kc) {
        const int row = wn * 32 + nf * 16 + l15;
        const int chunk = ((kc << 2) | lk) ^ (row & 7);
        fb[nf][kc] = *reinterpret_cast<const bf16x8*>((const char*)Ks + row * 128 + chunk * 16);
      }
#pragma unroll
    for (int mf = 0; mf < 2; ++mf)
#pragma unroll
      for (int nf = 0; nf < 2; ++nf)
#pragma unroll
        for (int kc = 0; kc < 2; ++kc)
          acc[mf][nf] = __builtin_amdgcn_mfma_f32_16x16x32_bf16(
              fa[mf][kc], fb[nf][kc], acc[mf][nf], 0, 0, 0);
    __syncthreads();
  }

  float* base = part + ((size_t)sp * BH_ + bh) * 4096;
#pragma unroll
  for (int mf = 0; mf < 2; ++mf)
#pragma unroll
    for (int nf = 0; nf < 2; ++nf)
#pragma unroll
      for (int r = 0; r < 4; ++r) {
        const int e = wm * 32 + mf * 16 + lk * 4 + r;
        const int d = wn * 32 + nf * 16 + l15;
        base[e * 64 + d] = acc[mf][nf][r];
      }
}

// ---------- 6) reduce 4 kv partials -> kvT bf16 ----------
__global__ void kv_reduce4(const float* __restrict__ part, u16* __restrict__ kvT) {
  const int i4 = (blockIdx.x * 256 + threadIdx.x) * 4;   // < 524288
  float4 s = *reinterpret_cast<const float4*>(part + i4);
#pragma unroll
  for (int sp = 1; sp < 4; ++sp) {
    float4 p = *reinterpret_cast<const float4*>(part + (size_t)sp * 524288 + i4);
    s.x += p.x; s.y += p.y; s.z += p.z; s.w += p.w;
  }
  u32 lo = (u32)f2bf(s.x) | ((u32)f2bf(s.y) << 16);
  u32 hi = (u32)f2bf(s.z) | ((u32)f2bf(s.w) << 16);
  uint2 o; o.x = lo; o.y = hi;
  *reinterpret_cast<uint2*>(kvT + i4) = o;
}

// ---------- 7) attn_gemm: attn[n][h*64+e] = sum_d qn[n][h*64+d]*kvT[e][d] ----------
__global__ void attn_gemm(const u16* __restrict__ qkv, const u16* __restrict__ kvT,
                          u16* __restrict__ attn) {
  const int bh = blockIdx.x, nt = blockIdx.y;
  const int b = bh >> 4, h = bh & 15;
  const int n0 = nt * 128;
  __shared__ __align__(16) u16 Qs[128 * 64];  // 16KB
  __shared__ __align__(16) u16 Ks[64 * 64];   // 8KB
  const int tid  = threadIdx.x;
  const int lane = tid & 63;
  const int wm   = tid >> 6;       // 0..3
  const int l15  = lane & 15;
  const int lk   = lane >> 4;

#pragma unroll
  for (int is = 0; is < 4; ++is) {
    const int lin   = is * 4096 + tid * 16;
    const int row   = lin >> 7;
    const int chunk = ((lin >> 4) & 7) ^ (row & 7);
    gload16(qkv + ((size_t)(b * N_ + n0 + row)) * 3072 + h * 64 + chunk * 8,
            (char*)Qs + lin);
  }
#pragma unroll
  for (int is = 0; is < 2; ++is) {
    const int lin   = is * 4096 + tid * 16;
    const int row   = lin >> 7;
    const int chunk = ((lin >> 4) & 7) ^ (row & 7);
    gload16(kvT + (size_t)bh * 4096 + row * 64 + chunk * 8, (char*)Ks + lin);
  }
  __syncthreads();

  bf16x8 fq[2][2], fk[4][2];
#pragma unroll
  for (int mf = 0; mf < 2; ++mf)
#pragma unroll
    for (int kc = 0; kc < 2; ++kc) {
      const int row = wm * 32 + mf * 16 + l15;
      const int chunk = ((kc << 2) | lk) ^ (row & 7);
      fq[mf][kc] = *reinterpret_cast<const bf16x8*>((const char*)Qs + row * 128 + chunk * 16);
    }
#pragma unroll
  for (int nf = 0; nf < 4; ++nf)
#pragma unroll
    for (int kc = 0; kc < 2; ++kc) {
      const int row = nf * 16 + l15;
      const int chunk = ((kc << 2) | lk) ^ (row & 7);
      fk[nf][kc] = *reinterpret_cast<const bf16x8*>((const char*)Ks + row * 128 + chunk * 16);
    }
  f32x4 acc[2][4] = {};
#pragma unroll
  for (int mf = 0; mf < 2; ++mf)
#pragma unroll
    for (int nf = 0; nf < 4; ++nf)
#pragma unroll
      for (int kc = 0; kc < 2; ++kc)
        acc[mf][nf] = __builtin_amdgcn_mfma_f32_16x16x32_bf16(
            fq[mf][kc], fk[nf][kc], acc[mf][nf], 0, 0, 0);

#pragma unroll
  for (int mf = 0; mf < 2; ++mf)
#pragma unroll
    for (int nf = 0; nf < 4; ++nf)
#pragma unroll
      for (int r = 0; r < 4; ++r) {
        const size_t row = (size_t)(b * N_ + n0 + wm * 32 + mf * 16 + lk * 4 + r);
        attn[row * 1024 + h * 64 + nf * 16 + l15] = f2bf(acc[mf][nf][r]);
      }
}

// ---------- workspace layout (bytes), within R2's proven footprint ----------
#define WS_XB     0ull            // bf16 xb [32768][1024]; then KT [128][64][4096]
#define WS_QKV    67108864ull     // bf16 [32768][3072]; q-cols normalized in place
#define WS_VT     268435456ull    // bf16 VT [128][64][4096]; then attn [32768][1024]
#define WS_WQKV   335544320ull    // bf16 [3072][1024]
#define WS_WPROJ  341835776ull    // bf16 [1024][1024]
#define WS_PART   343932928ull    // f32  [4][128][64][64] = 8.4MB
#define WS_KVT    360710144ull    // bf16 [128][64][64] = 1MB

extern "C" void kernel_launch(void* const* d_in, const int* in_sizes, int n_in,
                              void* d_out, int out_size, void* d_ws, size_t ws_size,
                              hipStream_t stream) {
  const float* x      = (const float*)d_in[0];
  const float* qkv_w  = (const float*)d_in[1];
  const float* qkv_b  = (const float*)d_in[2];
  const float* proj_w = (const float*)d_in[3];
  const float* proj_b = (const float*)d_in[4];

  char* ws = (char*)d_ws;
  u16*   xb      = (u16*)(ws + WS_XB);
  u16*   KT      = (u16*)(ws + WS_XB);      // overlays xb (dead after QKV gemm)
  u16*   qkv     = (u16*)(ws + WS_QKV);
  u16*   VT      = (u16*)(ws + WS_VT);
  u16*   attn    = (u16*)(ws + WS_VT);      // overlays VT (dead after kv_gemm)
  u16*   wqkv_t  = (u16*)(ws + WS_WQKV);
  u16*   wproj_t = (u16*)(ws + WS_WPROJ);
  float* part    = (float*)(ws + WS_PART);
  u16*   kvT     = (u16*)(ws + WS_KVT);

  cast_f32_bf16<<<2048, 256, 0, stream>>>(x, xb, (M_ * C_) / 4);
  transpose_cast<<<dim3(96, 32), 256, 0, stream>>>(qkv_w, wqkv_t, 1024, 3072);
  transpose_cast<<<dim3(32, 32), 256, 0, stream>>>(proj_w, wproj_t, 1024, 1024);
  // qkv = x @ qkv_w + b
  gemm256<3072, true><<<1536, 512, 0, stream>>>(xb, wqkv_t, qkv_b, qkv, 1024, 192);
  // q-norm in place; KT/VT transposed copies
  prep<<<dim3(128, 64), 256, 0, stream>>>(qkv, KT, VT);
  // kvT = (k_norm^T v)^T via A=VT, Bt=KT, split-K=4
  kv_gemm<<<dim3(128, 4), 256, 0, stream>>>(VT, KT, part);
  kv_reduce4<<<512, 256, 0, stream>>>(part, kvT);
  // attn = q_norm @ kv
  attn_gemm<<<dim3(128, 32), 256, 0, stream>>>(qkv, kvT, attn);
  // out = attn @ proj_w + b
  gemm256<1024, false><<<512, 512, 0, stream>>>(attn, wproj_t, proj_b, d_out, 1024, 64);
}